// Round 1
// baseline (64.732 us; speedup 1.0000x reference)
//
#include <hip/hip_runtime.h>

#define HH 1024
#define WW 1024
#define NPTS 512          // 16 segments * 32 samples = path points = edges
#define W_EPS 1e-6f       // drop edges whose row-weight is below this (err <= 512*eps)
#define CAP 64            // per-tile bucket capacity (fallback path if exceeded)

__device__ __forceinline__ float sigmoidf(float z) {
    // 1/(1+exp(-z)); __expf underflows to 0 for very negative z -> sigmoid==1 exactly. OK.
    float e = __expf(-z);
    return __builtin_amdgcn_rcpf(1.0f + e);
}

// Per-row working set (two rows per block).
struct RowCtx {
    float2 actXW[NPTS];    // compacted (x_cross, w)
    int    actTmin[NPTS];  // tiles t < tmin: edge fully saturated (acc += w)
    int    actTmax[NPTS];  // tiles in [tmin, tmax]: transition window (eval sigma)
    float2 bucket[16][CAP];
    int    cnt[16];
    float  satW[16];
    int    n_act;
};

__global__ __launch_bounds__(512) void render_kernel(
    const float* __restrict__ cp,     // 49 x 2 control points
    const float* __restrict__ color,  // 3 floats
    float* __restrict__ out)          // H x W x 4
{
    __shared__ float2 pts[NPTS];
    __shared__ RowCtx rc[2];

    const int tid  = threadIdx.x;
    const int half = tid >> 8;            // which of the block's 2 rows
    const int htid = tid & 255;
    const int y    = (blockIdx.x << 1) + half;
    const float yf = (float)y;

    if (htid == 0) rc[half].n_act = 0;
    if (htid < 16) rc[half].cnt[htid] = 0;

    // --- 1. Bezier path points: 512 threads, one point each (shared by both rows) ---
    {
        const int i = tid;
        int seg = i >> 5;
        int j = i & 31;
        float t = (float)j / 31.0f;           // linspace(0,1,32) — keep numerics identical
        float mt = 1.0f - t;
        int bb = 3 * seg * 2;
        float p0x = cp[bb + 0], p0y = cp[bb + 1];
        float p1x = cp[bb + 2], p1y = cp[bb + 3];
        float p2x = cp[bb + 4], p2y = cp[bb + 5];
        float p3x = cp[bb + 6], p3y = cp[bb + 7];
        float a0 = mt * mt * mt;
        float a1 = 3.0f * mt * mt * t;
        float a2 = 3.0f * mt * t * t;
        float a3 = t * t * t;
        pts[i] = make_float2(a0 * p0x + a1 * p1x + a2 * p2x + a3 * p3x,
                             a0 * p0y + a1 * p1y + a2 * p2y + a3 * p3y);
    }
    __syncthreads();

    // --- 2. per-edge weight for this half's row; compact + classify per 64-px tile ---
    // tile t covers x in [64t, 64t+63].
    //   saturated for all x in tile  <=> xc >= 64t+63+14  (sigma >= 1-8e-7)
    //   negligible for all x in tile <=> xc <= 64t-14     (sigma <= 8e-7)
    // Early-out: |w| > 1e-6 requires sigmoid(20t)>=1e-6 AND sigmoid(20(1-t))>=1e-6
    //   <=> t in [-0.691, 1.691]; the (-0.70, 1.70) window is strictly wider, so
    //   accept/reject decisions are IDENTICAL to the unguarded version.
    for (int e = htid; e < NPTS; e += 256) {
        float2 p = pts[e];
        float2 q = pts[(e + 1) & (NPTS - 1)];
        float dy = q.y - p.y;
        float t = (yf - p.y) / (dy + 1e-8f);
        if (t > -0.70f && t < 1.70f) {
            float c = (dy > 0.0f) ? 1.0f : ((dy < 0.0f) ? -1.0f : 0.0f);
            if (fabsf(dy) < 1e-6f) c = 0.0f;
            if (c != 0.0f) {
                float vt = sigmoidf(t * 20.0f) * sigmoidf((1.0f - t) * 20.0f);
                float w = vt * c;
                if (fabsf(w) > W_EPS) {
                    float dx = q.x - p.x;
                    float xc = p.x + t * dx;
                    int tmin = (int)ceilf((xc - 77.0f) * 0.015625f);   // /64
                    if (tmin < 0) tmin = 0;
                    if (tmin > 16) tmin = 16;
                    int tmax = (int)floorf((xc + 14.0f) * 0.015625f);
                    if (tmax > 15) tmax = 15;
                    int idx = atomicAdd(&rc[half].n_act, 1);
                    rc[half].actXW[idx] = make_float2(xc, w);
                    rc[half].actTmin[idx] = tmin;
                    rc[half].actTmax[idx] = tmax;
                    for (int tt = tmin; tt <= tmax; ++tt) {
                        int pos = atomicAdd(&rc[half].cnt[tt], 1);
                        if (pos < CAP) rc[half].bucket[tt][pos] = make_float2(xc, w);
                    }
                }
            }
        }
    }
    __syncthreads();

    const int n = rc[half].n_act;   // uniform within each 256-thread half

    // --- 2c. per-tile saturated sum: satW[t] = sum of w over edges with t < tmin ---
    {
        int grp = htid >> 4;        // tile 0..15
        int l16 = htid & 15;
        float partial = 0.0f;
        for (int i = l16; i < n; i += 16)
            if (grp < rc[half].actTmin[i]) partial += rc[half].actXW[i].y;
        partial += __shfl_down(partial, 8, 16);
        partial += __shfl_down(partial, 4, 16);
        partial += __shfl_down(partial, 2, 16);
        partial += __shfl_down(partial, 1, 16);
        if (l16 == 0) rc[half].satW[grp] = partial;
    }
    __syncthreads();

    // --- 3. pixel sweep: each half's 4 waves; wave wv handles tiles {wv, wv+4, wv+8, wv+12} ---
    const float cr = color[0], cg = color[1], cb = color[2];
    const int wv = (tid >> 6) & 3;
    const int lane = tid & 63;
    float4* orow = ((float4*)out) + y * WW;

    for (int k = 0; k < 4; ++k) {
        const int t = k * 4 + wv;
        const int x = t * 64 + lane;
        const float xf = (float)x;
        float acc;
        const int m = rc[half].cnt[t];
        if (m <= CAP) {
            acc = rc[half].satW[t];
            for (int j = 0; j < m; ++j) {
                float2 d = rc[half].bucket[t][j];    // wave-uniform broadcast
                acc = fmaf(d.y, sigmoidf(d.x - xf), acc);
            }
        } else {
            // overflow fallback: classified scan of the full compact list
            acc = 0.0f;
            for (int i = 0; i < n; ++i) {
                int tmin = rc[half].actTmin[i];
                if (t < tmin) {
                    acc += rc[half].actXW[i].y;
                } else if (t <= rc[half].actTmax[i]) {
                    float2 d = rc[half].actXW[i];
                    acc = fmaf(d.y, sigmoidf(d.x - xf), acc);
                }
            }
        }
        orow[x] = make_float4(cr, cg, cb, sigmoidf(4.0f * acc));
    }
}

extern "C" void kernel_launch(void* const* d_in, const int* in_sizes, int n_in,
                              void* d_out, int out_size, void* d_ws, size_t ws_size,
                              hipStream_t stream) {
    const float* cp = (const float*)d_in[0];
    const float* color = (const float*)d_in[1];
    float* out = (float*)d_out;
    render_kernel<<<HH / 2, 512, 0, stream>>>(cp, color, out);
}